// Round 1
// baseline (1252.583 us; speedup 1.0000x reference)
//
#include <hip/hip_runtime.h>
#include <hip/hip_bf16.h>

// Problem constants (x: [32768,512] fp32, centroids: [8192,512] fp32)
#define N_ROWS 32768
#define DIM    512
#define K_CENT 8192

// Output layout (flat fp32): x_q [N*D] | loss [1] | indices-as-float [N]
#define LOSS_OFF 16777216u
#define IDX_OFF  16777217u

// Main-kernel tiling
#define BM    128          // rows per block
#define BKT   128          // centroid cols per block k-tile
#define KHALF 4096         // K split across gridDim.y = 2
#define NKT   (KHALF / BKT)          // 32 k-tiles
#define LDS_STRIDE 40      // bf16 elems per 32-d row (+8 pad -> 80B stride, 2-way banks = free)

typedef __bf16 bf16x8 __attribute__((ext_vector_type(8)));
typedef float  f32x4  __attribute__((ext_vector_type(4)));

// fp32 -> bf16 hi/lo split, RNE both stages. hi+lo represents x to ~2^-18 rel.
__device__ __forceinline__ void split4(float4 v, uint2& hi, uint2& lo) {
    float f[4] = {v.x, v.y, v.z, v.w};
    unsigned short h[4], l[4];
#pragma unroll
    for (int i = 0; i < 4; ++i) {
        unsigned u = __float_as_uint(f[i]);
        unsigned short hs = (unsigned short)((u + 0x7fffu + ((u >> 16) & 1u)) >> 16);
        float hf = __uint_as_float(((unsigned)hs) << 16);
        float res = f[i] - hf;                    // exact (Sterbenz)
        unsigned w = __float_as_uint(res);
        unsigned short ls = (unsigned short)((w + 0x7fffu + ((w >> 16) & 1u)) >> 16);
        h[i] = hs; l[i] = ls;
    }
    hi.x = (unsigned)h[0] | ((unsigned)h[1] << 16);
    hi.y = (unsigned)h[2] | ((unsigned)h[3] << 16);
    lo.x = (unsigned)l[0] | ((unsigned)l[1] << 16);
    lo.y = (unsigned)l[2] | ((unsigned)l[3] << 16);
}

// ---------------- k1: c_norm[k] = sum_d c[k][d]^2  -> stashed at out[IDX_OFF..+K)
__global__ void __launch_bounds__(256) cnorm_kernel(const float* __restrict__ cen,
                                                    float* __restrict__ cnp) {
    const int wave = threadIdx.x >> 6, lane = threadIdx.x & 63;
    const int row  = blockIdx.x * 4 + wave;
    const float* p = cen + (size_t)row * DIM + lane * 8;
    float4 a = *(const float4*)p;
    float4 b = *(const float4*)(p + 4);
    float s = a.x*a.x + a.y*a.y + a.z*a.z + a.w*a.w
            + b.x*b.x + b.y*b.y + b.z*b.z + b.w*b.w;
#pragma unroll
    for (int off = 32; off; off >>= 1) s += __shfl_down(s, off, 64);
    if (lane == 0) cnp[row] = s;
}

// ---------------- k2: bf16x3-split MFMA distance GEMM + per-row top-2 argmin
// grid (256, 2): blockIdx.x = row tile, blockIdx.y = K half.
// Writes per row n: out[n*512 + h*4 + {0,1,2,3}] = {d1, i1, d2, i2} for half h.
__global__ void __launch_bounds__(256, 2) vq_main(const float* __restrict__ xg,
                                                  const float* __restrict__ cg,
                                                  const float* __restrict__ cnp,
                                                  float* __restrict__ outp) {
    __shared__ __align__(16) unsigned short xs_hi[BM * LDS_STRIDE];
    __shared__ __align__(16) unsigned short xs_lo[BM * LDS_STRIDE];
    __shared__ __align__(16) unsigned short cs_hi[BKT * LDS_STRIDE];
    __shared__ __align__(16) unsigned short cs_lo[BKT * LDS_STRIDE];
    __shared__ float sh_d1[2][BM]; __shared__ int sh_i1[2][BM];
    __shared__ float sh_d2[2][BM]; __shared__ int sh_i2[2][BM];

    const int tid  = threadIdx.x;
    const int wave = tid >> 6, lane = tid & 63;
    const int wm   = wave >> 1, wk = wave & 1;      // 2x2 waves: wm over rows, wk over cols
    const int lr   = lane & 15, quad = lane >> 4;
    const int nbase = blockIdx.x * BM;
    const int h     = blockIdx.y;
    const int kc0   = h * KHALF;
    const int rbase = wm * 64;
    const int cbase = wk * 64;

    // Staging geometry: thread loads float4 #j at row r0+32j, col c4*4 of the 128x32 tile
    const int r0 = tid >> 3, c4 = tid & 7;
    const float* xbase = xg + (size_t)(nbase + r0) * DIM + c4 * 4;
    const float* cbase_p = cg + (size_t)r0 * DIM + c4 * 4;
    const int lds_w0 = r0 * LDS_STRIDE + c4 * 4;

    // Fragment LDS offsets (ushort units) — invariant over kt/d
    int aoff[4], boff[4];
#pragma unroll
    for (int t = 0; t < 4; ++t) {
        aoff[t] = (rbase + t * 16 + lr) * LDS_STRIDE + quad * 8;
        boff[t] = (cbase + t * 16 + lr) * LDS_STRIDE + quad * 8;
    }

    // Per-(mt,reg) running top-2 over this lane's col subset
    float rd1[4][4], rd2[4][4];
    int   ri1[4][4], ri2[4][4];
#pragma unroll
    for (int mt = 0; mt < 4; ++mt)
#pragma unroll
        for (int r = 0; r < 4; ++r) {
            rd1[mt][r] = 1e30f; rd2[mt][r] = 1e30f;
            ri1[mt][r] = 0x7fffffff; ri2[mt][r] = 0x7fffffff;
        }

    for (int kt = 0; kt < NKT; ++kt) {
        const int kc = kc0 + kt * BKT;
        f32x4 acc[4][4];
#pragma unroll
        for (int mt = 0; mt < 4; ++mt)
#pragma unroll
            for (int t = 0; t < 4; ++t) { acc[mt][t].x = 0.f; acc[mt][t].y = 0.f; acc[mt][t].z = 0.f; acc[mt][t].w = 0.f; }

        for (int dsb = 0; dsb < 16; ++dsb) {     // 32-wide d-steps over DIM=512
            const int d0 = dsb * 32;
            __syncthreads();                     // prior reads done before restage
#pragma unroll
            for (int j = 0; j < 4; ++j) {
                uint2 hi, lo;
                float4 vx = *(const float4*)(xbase + (size_t)j * 32 * DIM + d0);
                split4(vx, hi, lo);
                *(uint2*)&xs_hi[lds_w0 + j * 32 * LDS_STRIDE] = hi;
                *(uint2*)&xs_lo[lds_w0 + j * 32 * LDS_STRIDE] = lo;
                float4 vc = *(const float4*)(cbase_p + (size_t)(kc + j * 32) * DIM + d0);
                split4(vc, hi, lo);
                *(uint2*)&cs_hi[lds_w0 + j * 32 * LDS_STRIDE] = hi;
                *(uint2*)&cs_lo[lds_w0 + j * 32 * LDS_STRIDE] = lo;
            }
            __syncthreads();

            bf16x8 bh[4], bl[4];
#pragma unroll
            for (int t = 0; t < 4; ++t) {
                bh[t] = *(const bf16x8*)&cs_hi[boff[t]];
                bl[t] = *(const bf16x8*)&cs_lo[boff[t]];
            }
#pragma unroll
            for (int mt = 0; mt < 4; ++mt) {
                bf16x8 ah = *(const bf16x8*)&xs_hi[aoff[mt]];
                bf16x8 al = *(const bf16x8*)&xs_lo[aoff[mt]];
#pragma unroll
                for (int t = 0; t < 4; ++t) {
                    acc[mt][t] = __builtin_amdgcn_mfma_f32_16x16x32_bf16(ah, bh[t], acc[mt][t], 0, 0, 0);
                    acc[mt][t] = __builtin_amdgcn_mfma_f32_16x16x32_bf16(ah, bl[t], acc[mt][t], 0, 0, 0);
                    acc[mt][t] = __builtin_amdgcn_mfma_f32_16x16x32_bf16(al, bh[t], acc[mt][t], 0, 0, 0);
                }
            }
        }

        // Epilogue: dist proxy = c_norm - 2*S (x_norm is row-constant, irrelevant to argmin)
#pragma unroll
        for (int t = 0; t < 4; ++t) {
            const int col = kc + cbase + t * 16 + lr;
            const float cn = cnp[col];
#pragma unroll
            for (int mt = 0; mt < 4; ++mt)
#pragma unroll
                for (int r = 0; r < 4; ++r) {
                    float d = fmaf(-2.f, acc[mt][t][r], cn);
                    bool b1 = d < rd1[mt][r];
                    bool b2 = d < rd2[mt][r];
                    float o1 = rd1[mt][r]; int oi1 = ri1[mt][r];
                    rd2[mt][r] = b1 ? o1 : (b2 ? d : rd2[mt][r]);
                    ri2[mt][r] = b1 ? oi1 : (b2 ? col : ri2[mt][r]);
                    rd1[mt][r] = b1 ? d : o1;
                    ri1[mt][r] = b1 ? col : oi1;
                }
        }
    }

    // Cross-lane top-2 merge over the 16 lanes sharing each row (xor butterfly)
#pragma unroll
    for (int mt = 0; mt < 4; ++mt)
#pragma unroll
        for (int r = 0; r < 4; ++r) {
            float d1 = rd1[mt][r], d2 = rd2[mt][r];
            int   i1 = ri1[mt][r], i2 = ri2[mt][r];
#pragma unroll
            for (int s = 1; s < 16; s <<= 1) {
                float od1 = __shfl_xor(d1, s, 64), od2 = __shfl_xor(d2, s, 64);
                int   oi1 = __shfl_xor(i1, s, 64), oi2 = __shfl_xor(i2, s, 64);
                bool ol = (od1 < d1) || (od1 == d1 && oi1 < i1);
                float n1 = ol ? od1 : d1;  int ni1 = ol ? oi1 : i1;
                float ca = ol ? d1 : od1;  int cia = ol ? i1 : oi1;   // loser's first
                float cb = ol ? od2 : d2;  int cib = ol ? oi2 : i2;   // winner's second
                bool bl2 = (cb < ca) || (cb == ca && cib < cia);
                d1 = n1; i1 = ni1;
                d2 = bl2 ? cb : ca; i2 = bl2 ? cib : cia;
            }
            if (lr == 0) {
                int rl = rbase + mt * 16 + quad * 4 + r;
                sh_d1[wk][rl] = d1; sh_i1[wk][rl] = i1;
                sh_d2[wk][rl] = d2; sh_i2[wk][rl] = i2;
            }
        }
    __syncthreads();

    // Merge wk=0/1 top-2 lists, write this half's top-2 into the row's own cells
    if (tid < BM) {
        float a1 = sh_d1[0][tid], a2 = sh_d2[0][tid];
        int  ai1 = sh_i1[0][tid], ai2 = sh_i2[0][tid];
        float b1 = sh_d1[1][tid], b2 = sh_d2[1][tid];
        int  bi1 = sh_i1[1][tid], bi2 = sh_i2[1][tid];
        bool ol = (b1 < a1) || (b1 == a1 && bi1 < ai1);
        float m1 = ol ? b1 : a1;  int mi1 = ol ? bi1 : ai1;
        float ca = ol ? a1 : b1;  int cia = ol ? ai1 : bi1;
        float cb = ol ? b2 : a2;  int cib = ol ? bi2 : ai2;
        bool bl2 = (cb < ca) || (cb == ca && cib < cia);
        float m2 = bl2 ? cb : ca; int mi2 = bl2 ? cib : cia;
        float* cell = outp + (size_t)(nbase + tid) * DIM + h * 4;
        cell[0] = m1; cell[1] = (float)mi1; cell[2] = m2; cell[3] = (float)mi2;
    }
}

// ---------------- k3: fp64-exact refine over <=4 candidates + gather + loss
__global__ void __launch_bounds__(256) vq_gather(const float* __restrict__ xg,
                                                 const float* __restrict__ cg,
                                                 float* __restrict__ outp) {
    __shared__ float ls[4];
    const int wave = threadIdx.x >> 6, lane = threadIdx.x & 63;
    const int n = blockIdx.x * 4 + wave;
    float* row = outp + (size_t)n * DIM;

    // Candidate indices from the row's first 8 cells (read BEFORE any write)
    int cand[4];
    cand[0] = (int)row[1]; cand[1] = (int)row[3];
    cand[2] = (int)row[5]; cand[3] = (int)row[7];

    const float* xr = xg + (size_t)n * DIM + lane * 8;
    float4 xa = *(const float4*)xr;
    float4 xb = *(const float4*)(xr + 4);

    double best_d = 1e300; int best_i = 0x7fffffff;
#pragma unroll
    for (int c = 0; c < 4; ++c) {
        const int k = cand[c];
        const float* cr = cg + (size_t)k * DIM + lane * 8;
        float4 ca = *(const float4*)cr;
        float4 cb = *(const float4*)(cr + 4);
        double s = 0.0, t;
        t = (double)xa.x - (double)ca.x; s += t * t;
        t = (double)xa.y - (double)ca.y; s += t * t;
        t = (double)xa.z - (double)ca.z; s += t * t;
        t = (double)xa.w - (double)ca.w; s += t * t;
        t = (double)xb.x - (double)cb.x; s += t * t;
        t = (double)xb.y - (double)cb.y; s += t * t;
        t = (double)xb.z - (double)cb.z; s += t * t;
        t = (double)xb.w - (double)cb.w; s += t * t;
#pragma unroll
        for (int off = 32; off; off >>= 1) s += __shfl_down(s, off, 64);
        s = __shfl(s, 0, 64);
        if (s < best_d || (s == best_d && k < best_i)) { best_d = s; best_i = k; }
    }

    // Gather winning centroid row and write x_q (straight-through: x_q == q)
    const float* qr = cg + (size_t)best_i * DIM + lane * 8;
    float4 qa = *(const float4*)qr;
    float4 qb = *(const float4*)(qr + 4);
    *(float4*)(row + lane * 8)     = qa;
    *(float4*)(row + lane * 8 + 4) = qb;

    if (lane == 0) {
        outp[IDX_OFF + n] = (float)best_i;
        ls[wave] = (float)best_d;     // row's Sum (q-x)^2, fp64-exact
    }
    __syncthreads();
    if (threadIdx.x == 0) atomicAdd(outp + LOSS_OFF, ls[0] + ls[1] + ls[2] + ls[3]);
}

// ---------------- k4: loss = (codebook + 0.25*commitment) = 1.25 * mean
__global__ void finalize_kernel(float* __restrict__ outp) {
    if (threadIdx.x == 0) outp[LOSS_OFF] *= (1.25f / 16777216.f);
}

extern "C" void kernel_launch(void* const* d_in, const int* in_sizes, int n_in,
                              void* d_out, int out_size, void* d_ws, size_t ws_size,
                              hipStream_t stream) {
    const float* x   = (const float*)d_in[0];
    const float* cen = (const float*)d_in[1];
    float* out = (float*)d_out;
    float* cnp = out + IDX_OFF;   // stash c_norm in the indices slot (overwritten by k3 at the end)

    hipMemsetAsync((void*)(out + LOSS_OFF), 0, sizeof(float), stream);
    cnorm_kernel<<<K_CENT / 4, 256, 0, stream>>>(cen, cnp);
    dim3 g2(N_ROWS / BM, 2);
    vq_main<<<g2, 256, 0, stream>>>(x, cen, cnp, out);
    vq_gather<<<N_ROWS / 4, 256, 0, stream>>>(x, cen, out);
    finalize_kernel<<<1, 64, 0, stream>>>(out);
}

// Round 3
// 652.927 us; speedup vs baseline: 1.9184x; 1.9184x over previous
//
#include <hip/hip_runtime.h>
#include <hip/hip_bf16.h>

// Problem: x [32768,512] fp32, centroids [8192,512] fp32
#define N_ROWS 32768
#define DIM    512
#define K_CENT 8192

// Output (flat fp32): x_q [N*D] | loss [1] | indices-as-float [N]
#define LOSS_OFF 16777216u
#define IDX_OFF  16777217u

// Scratch layout INSIDE the x_q region of d_out (64 MB), used during phase A,
// fully overwritten by the final gather kernel (which reads nothing from it):
//   x_hi : ushort[N*D]      bytes [0, 32M)
//   c_hi : ushort[K*D]      bytes [32M, 40M)
//   cnorm: float[K]         bytes [40M, 40M+32K)
//   cand : float[N*2*8]     bytes [40M+32K, +2M)  per (row,half): {d,i}x4 sorted
#define XH_OFF_B   0u
#define CH_OFF_B   33554432u
#define CN_OFF_B   41943040u
#define CAND_OFF_B 41975808u

#define BM   128
#define BN   128
#define KHALF 4096
#define NKT  (KHALF / BN)      // 32

typedef __bf16 bf16x8 __attribute__((ext_vector_type(8)));
typedef float  f32x4  __attribute__((ext_vector_type(4)));

__device__ __forceinline__ unsigned short f2bf(float f) {
    unsigned u = __float_as_uint(f);
    return (unsigned short)((u + 0x7fffu + ((u >> 16) & 1u)) >> 16);
}

// Async global->LDS, 16B per lane. LDS dest = wave-uniform base + lane*16.
__device__ __forceinline__ void glds16(void* lds, const void* g) {
    __builtin_amdgcn_global_load_lds(
        (const __attribute__((address_space(1))) unsigned*)g,
        (__attribute__((address_space(3))) unsigned*)lds, 16, 0, 0);
}

// ---------------- k0: one-shot fp32 -> bf16(hi) conversion + c_norm
__global__ void __launch_bounds__(256) convert_kernel(const float* __restrict__ x,
                                                      const float* __restrict__ c,
                                                      unsigned short* __restrict__ xh,
                                                      unsigned short* __restrict__ ch,
                                                      float* __restrict__ cnp) {
    const int wave = threadIdx.x >> 6, lane = threadIdx.x & 63;
    const int gid = blockIdx.x * 4 + wave;
    if (gid < N_ROWS) {
        const float* p = x + (size_t)gid * DIM + lane * 8;
        float4 a = *(const float4*)p, b = *(const float4*)(p + 4);
        uint4 w;
        w.x = (unsigned)f2bf(a.x) | ((unsigned)f2bf(a.y) << 16);
        w.y = (unsigned)f2bf(a.z) | ((unsigned)f2bf(a.w) << 16);
        w.z = (unsigned)f2bf(b.x) | ((unsigned)f2bf(b.y) << 16);
        w.w = (unsigned)f2bf(b.z) | ((unsigned)f2bf(b.w) << 16);
        *(uint4*)(xh + (size_t)gid * DIM + lane * 8) = w;
    } else {
        const int cr = gid - N_ROWS;
        const float* p = c + (size_t)cr * DIM + lane * 8;
        float4 a = *(const float4*)p, b = *(const float4*)(p + 4);
        uint4 w;
        w.x = (unsigned)f2bf(a.x) | ((unsigned)f2bf(a.y) << 16);
        w.y = (unsigned)f2bf(a.z) | ((unsigned)f2bf(a.w) << 16);
        w.z = (unsigned)f2bf(b.x) | ((unsigned)f2bf(b.y) << 16);
        w.w = (unsigned)f2bf(b.z) | ((unsigned)f2bf(b.w) << 16);
        *(uint4*)(ch + (size_t)cr * DIM + lane * 8) = w;
        float s = a.x*a.x + a.y*a.y + a.z*a.z + a.w*a.w
                + b.x*b.x + b.y*b.y + b.z*b.z + b.w*b.w;
#pragma unroll
        for (int off = 32; off; off >>= 1) s += __shfl_down(s, off, 64);
        if (lane == 0) cnp[cr] = s;
    }
}

// compare-exchange on (d,i) pairs, lexicographic
__device__ __forceinline__ void ce(float& da, int& ia, float& db, int& ib) {
    bool sw = (db < da) || (db == da && ib < ia);
    float td = sw ? db : da; int ti = sw ? ib : ia;
    float ud = sw ? da : db; int ui = sw ? ia : ib;
    da = td; ia = ti; db = ud; ib = ui;
}
__device__ __forceinline__ void lmin(float da, int ia, float db, int ib,
                                     float& od, int& oi) {
    bool sw = (db < da) || (db == da && ib < ia);
    od = sw ? db : da; oi = sw ? ib : ia;
}

// ---------------- k1: pure bf16 MFMA proxy GEMM + per-row top-4 per half
// grid (256, 2): blockIdx.x = 128-row tile, blockIdx.y = K half (4096 cols).
__global__ void __launch_bounds__(256, 2) vq_main(const unsigned short* __restrict__ xh,
                                                  const unsigned short* __restrict__ ch,
                                                  const float* __restrict__ cnp,
                                                  float* __restrict__ cand) {
    __shared__ __align__(16) unsigned short xs[BM * 32];   // 8 KB, row-major 64B rows
    __shared__ __align__(16) unsigned short cs[BN * 32];   // 8 KB
    __shared__ float sh_d[2][BM][4];                       // 4 KB
    __shared__ int   sh_i[2][BM][4];                       // 4 KB

    const int tid  = threadIdx.x;
    const int wave = tid >> 6, lane = tid & 63;
    const int wm   = wave >> 1, wk = wave & 1;
    const int lr   = lane & 15, quad = lane >> 4;
    const int nbase = blockIdx.x * BM;
    const int h     = blockIdx.y;
    const int kc0   = h * KHALF;

    // staging: wave stages rows [wave*32, wave*32+32), 16 rows per glds16
    const int srow = wave * 32 + (lane >> 2);
    const int scol = (lane & 3) * 8;
    const unsigned short* xg0 = xh + (size_t)(nbase + srow) * DIM + scol;
    unsigned short* xd0 = &xs[wave * 1024];
    unsigned short* xd1 = &xs[wave * 1024 + 512];
    unsigned short* cd0 = &cs[wave * 1024];
    unsigned short* cd1 = &cs[wave * 1024 + 512];

    int aoff[4], boff[4];
#pragma unroll
    for (int t = 0; t < 4; ++t) {
        aoff[t] = (wm * 64 + t * 16 + lr) * 32 + quad * 8;
        boff[t] = (wk * 64 + t * 16 + lr) * 32 + quad * 8;
    }

    float rd1[4][4], rd2[4][4];
    int   ri1[4][4], ri2[4][4];
#pragma unroll
    for (int mt = 0; mt < 4; ++mt)
#pragma unroll
        for (int r = 0; r < 4; ++r) {
            rd1[mt][r] = 1e30f; rd2[mt][r] = 1e30f;
            ri1[mt][r] = 0x7ffffff0; ri2[mt][r] = 0x7ffffff1;
        }

    for (int kt = 0; kt < NKT; ++kt) {
        const int kc = kc0 + kt * BN;
        const unsigned short* cg0 = ch + (size_t)(kc + srow) * DIM + scol;
        f32x4 acc[4][4];
#pragma unroll
        for (int mt = 0; mt < 4; ++mt)
#pragma unroll
            for (int t = 0; t < 4; ++t) { acc[mt][t].x = 0.f; acc[mt][t].y = 0.f; acc[mt][t].z = 0.f; acc[mt][t].w = 0.f; }

        for (int dsb = 0; dsb < 16; ++dsb) {
            const int d0 = dsb * 32;
            __syncthreads();                    // prior LDS reads done
            glds16(xd0, xg0 + d0);
            glds16(xd1, xg0 + (size_t)16 * DIM + d0);
            glds16(cd0, cg0 + d0);
            glds16(cd1, cg0 + (size_t)16 * DIM + d0);
            __syncthreads();                    // drains vmcnt (glds) too

            bf16x8 bfr[4];
#pragma unroll
            for (int t = 0; t < 4; ++t) bfr[t] = *(const bf16x8*)&cs[boff[t]];
#pragma unroll
            for (int mt = 0; mt < 4; ++mt) {
                bf16x8 a = *(const bf16x8*)&xs[aoff[mt]];
#pragma unroll
                for (int t = 0; t < 4; ++t)
                    acc[mt][t] = __builtin_amdgcn_mfma_f32_16x16x32_bf16(a, bfr[t], acc[mt][t], 0, 0, 0);
            }
        }

        // epilogue: proxy dist = c_norm - 2*S (x_norm row-constant), top-2/lane
#pragma unroll
        for (int t = 0; t < 4; ++t) {
            const int col = kc + wk * 64 + t * 16 + lr;
            const float cnv = cnp[col];
#pragma unroll
            for (int mt = 0; mt < 4; ++mt)
#pragma unroll
                for (int r = 0; r < 4; ++r) {
                    float d = fmaf(-2.f, acc[mt][t][r], cnv);
                    bool b1 = d < rd1[mt][r];
                    bool b2 = d < rd2[mt][r];
                    float o1 = rd1[mt][r]; int oi1 = ri1[mt][r];
                    rd2[mt][r] = b1 ? o1 : (b2 ? d : rd2[mt][r]);
                    ri2[mt][r] = b1 ? oi1 : (b2 ? col : ri2[mt][r]);
                    rd1[mt][r] = b1 ? d : o1;
                    ri1[mt][r] = b1 ? col : oi1;
                }
        }
    }

    // Merge 16 lanes/row (each holding sorted top-2) -> sorted top-4 per (wk,row)
#pragma unroll
    for (int mt = 0; mt < 4; ++mt)
#pragma unroll
        for (int r = 0; r < 4; ++r) {
            float a0 = rd1[mt][r], a1 = rd2[mt][r], a2 = 1e30f, a3 = 1e30f;
            int   i0 = ri1[mt][r], i1 = ri2[mt][r], i2 = 0x7ffffff2, i3 = 0x7ffffff3;
#pragma unroll
            for (int s = 1; s < 16; s <<= 1) {
                float p0 = __shfl_xor(a0, s, 64), p1 = __shfl_xor(a1, s, 64);
                float p2 = __shfl_xor(a2, s, 64), p3 = __shfl_xor(a3, s, 64);
                int   q0 = __shfl_xor(i0, s, 64), q1 = __shfl_xor(i1, s, 64);
                int   q2 = __shfl_xor(i2, s, 64), q3 = __shfl_xor(i3, s, 64);
                float l0, l1, l2, l3; int m0, m1, m2, m3;
                lmin(a0, i0, p3, q3, l0, m0);
                lmin(a1, i1, p2, q2, l1, m1);
                lmin(a2, i2, p1, q1, l2, m2);
                lmin(a3, i3, p0, q0, l3, m3);
                ce(l0, m0, l2, m2); ce(l1, m1, l3, m3);
                ce(l0, m0, l1, m1); ce(l2, m2, l3, m3);
                a0 = l0; a1 = l1; a2 = l2; a3 = l3;
                i0 = m0; i1 = m1; i2 = m2; i3 = m3;
            }
            if (lr == 0) {
                const int rl = wm * 64 + mt * 16 + quad * 4 + r;
                sh_d[wk][rl][0] = a0; sh_i[wk][rl][0] = i0;
                sh_d[wk][rl][1] = a1; sh_i[wk][rl][1] = i1;
                sh_d[wk][rl][2] = a2; sh_i[wk][rl][2] = i2;
                sh_d[wk][rl][3] = a3; sh_i[wk][rl][3] = i3;
            }
        }
    __syncthreads();

    // Cross-wk merge: two sorted-4 lists -> this half's true top-4 per row.
    if (tid < BM) {
        float a0 = sh_d[0][tid][0], a1 = sh_d[0][tid][1];
        float a2 = sh_d[0][tid][2], a3 = sh_d[0][tid][3];
        int   i0 = sh_i[0][tid][0], i1 = sh_i[0][tid][1];
        int   i2 = sh_i[0][tid][2], i3 = sh_i[0][tid][3];
        float b0 = sh_d[1][tid][0], b1 = sh_d[1][tid][1];
        float b2 = sh_d[1][tid][2], b3 = sh_d[1][tid][3];
        int   j0 = sh_i[1][tid][0], j1 = sh_i[1][tid][1];
        int   j2 = sh_i[1][tid][2], j3 = sh_i[1][tid][3];
        float l0, l1, l2, l3; int m0, m1, m2, m3;
        lmin(a0, i0, b3, j3, l0, m0);
        lmin(a1, i1, b2, j2, l1, m1);
        lmin(a2, i2, b1, j1, l2, m2);
        lmin(a3, i3, b0, j0, l3, m3);
        ce(l0, m0, l2, m2); ce(l1, m1, l3, m3);
        ce(l0, m0, l1, m1); ce(l2, m2, l3, m3);
        float* cell = cand + ((size_t)(nbase + tid) * 2 + h) * 8;
        cell[0] = l0; cell[1] = (float)m0;
        cell[2] = l1; cell[3] = (float)m1;
        cell[4] = l2; cell[5] = (float)m2;
        cell[6] = l3; cell[7] = (float)m3;
    }
}

// ---------------- k2: fp64-exact refine over 8 candidates; idx + loss
__global__ void __launch_bounds__(256) vq_refine(const float* __restrict__ x,
                                                 const float* __restrict__ cg,
                                                 const float* __restrict__ cand,
                                                 float* __restrict__ outp) {
    __shared__ double ls[4];
    const int wave = threadIdx.x >> 6, lane = threadIdx.x & 63;
    const int n = blockIdx.x * 4 + wave;
    const float* cell = cand + (size_t)n * 16;
    int kid[8];
#pragma unroll
    for (int j = 0; j < 8; ++j) kid[j] = (int)cell[2 * j + 1];

    const float* xr = x + (size_t)n * DIM + lane * 8;
    float4 xa = *(const float4*)xr;
    float4 xb = *(const float4*)(xr + 4);

    double bd = 1e300; int bi = 0x7fffffff;
#pragma unroll
    for (int j = 0; j < 8; ++j) {
        const int k = kid[j];
        const float* cr = cg + (size_t)k * DIM + lane * 8;
        float4 ca = *(const float4*)cr;
        float4 cb = *(const float4*)(cr + 4);
        double s = 0.0, t;
        t = (double)xa.x - (double)ca.x; s += t * t;
        t = (double)xa.y - (double)ca.y; s += t * t;
        t = (double)xa.z - (double)ca.z; s += t * t;
        t = (double)xa.w - (double)ca.w; s += t * t;
        t = (double)xb.x - (double)cb.x; s += t * t;
        t = (double)xb.y - (double)cb.y; s += t * t;
        t = (double)xb.z - (double)cb.z; s += t * t;
        t = (double)xb.w - (double)cb.w; s += t * t;
#pragma unroll
        for (int off = 32; off; off >>= 1) s += __shfl_down(s, off, 64);
        s = __shfl(s, 0, 64);
        if (s < bd || (s == bd && k < bi)) { bd = s; bi = k; }
    }
    if (lane == 0) { outp[IDX_OFF + n] = (float)bi; ls[wave] = bd; }
    __syncthreads();
    if (threadIdx.x == 0)
        atomicAdd(outp + LOSS_OFF, (float)(ls[0] + ls[1] + ls[2] + ls[3]));
}

// ---------------- k3: loss scale
__global__ void finalize_kernel(float* __restrict__ outp) {
    if (threadIdx.x == 0) outp[LOSS_OFF] *= (1.25f / 16777216.f);
}

// ---------------- k4: gather x_q from final indices (reads only idx + centroids)
__global__ void __launch_bounds__(256) vq_gather(const float* __restrict__ cg,
                                                 float* __restrict__ outp) {
    const int wave = threadIdx.x >> 6, lane = threadIdx.x & 63;
    const int n = blockIdx.x * 4 + wave;
    const int k = (int)outp[IDX_OFF + n];
    const float* cr = cg + (size_t)k * DIM + lane * 8;
    float4 a = *(const float4*)cr;
    float4 b = *(const float4*)(cr + 4);
    float* row = outp + (size_t)n * DIM + lane * 8;
    *(float4*)row = a;
    *(float4*)(row + 4) = b;
}

extern "C" void kernel_launch(void* const* d_in, const int* in_sizes, int n_in,
                              void* d_out, int out_size, void* d_ws, size_t ws_size,
                              hipStream_t stream) {
    const float* x   = (const float*)d_in[0];
    const float* cen = (const float*)d_in[1];
    float* out = (float*)d_out;

    unsigned short* xh = (unsigned short*)((char*)d_out + XH_OFF_B);
    unsigned short* chp = (unsigned short*)((char*)d_out + CH_OFF_B);
    float* cnp  = (float*)((char*)d_out + CN_OFF_B);
    float* cand = (float*)((char*)d_out + CAND_OFF_B);

    hipMemsetAsync((void*)(out + LOSS_OFF), 0, sizeof(float), stream);
    convert_kernel<<<(N_ROWS + K_CENT) / 4, 256, 0, stream>>>(x, cen, xh, chp, cnp);
    dim3 g2(N_ROWS / BM, 2);
    vq_main<<<g2, 256, 0, stream>>>(xh, chp, cnp, cand);
    vq_refine<<<N_ROWS / 4, 256, 0, stream>>>(x, cen, cand, out);
    finalize_kernel<<<1, 64, 0, stream>>>(out);
    vq_gather<<<N_ROWS / 4, 256, 0, stream>>>(cen, out);
}